// Round 5
// baseline (485.715 us; speedup 1.0000x reference)
//
#include <hip/hip_runtime.h>

#define N_NODES 100000
#define N_EDGES 1600000
#define D_FEAT 32

#define BSH 7                 // bucket = dst >> 7  (128 nodes per bucket)
#define BMASK 127
#define NB 782                // ceil(100000/128)
#define CAPB 2432             // per-bucket capacity (mean 2048, ~8.5 sigma pad)

#define P1_BS 512
#define P1_TILE 4096          // 8 edges/thread
#define P1_CAP 16             // staging per bucket per block (mean ~5.2)

#define ACCW 33               // padded acc row: bank=(dstl+8q+j)%32 spreads banks

// ws layout (4-byte words):
//   cursorA [1024]        int    per-bucket fill cursors (init to b*CAPB)
//   deg     [N_NODES]     int    in-degree (global atomics from bucket pass)
//   dinv    [N_NODES]     float  1/sqrt(max(deg,1))
//   pairs   [NB*CAPB]     int    packed (src<<7)|(dst&127), bucket-grouped
//   sfeat   [N_NODES*16]  uint   bf16-packed feat*dinv (2 feats per uint)

typedef float v4f __attribute__((ext_vector_type(4)));   // native vec for nontemporal builtins

static __device__ __forceinline__ unsigned pack_bf16(float a, float b) {
    unsigned ua = __float_as_uint(a);
    unsigned ub = __float_as_uint(b);
    ua = (ua + 0x7FFFu + ((ua >> 16) & 1u)) >> 16;   // RNE
    ub = (ub + 0x7FFFu + ((ub >> 16) & 1u)) >> 16;
    return (ua & 0xFFFFu) | (ub << 16);
}

__global__ void __launch_bounds__(256)
init_kernel(int* __restrict__ cursorA, int* __restrict__ deg) {
    int i = blockIdx.x * 256 + threadIdx.x;
    if (i < NB) cursorA[i] = i * CAPB;
    if (i < N_NODES) deg[i] = 0;
}

// Pass 1: bucket edges by dst>>7 with LDS staging -> coalesced runs into
// fixed per-bucket regions. Slot-parallel drain. Also counts in-degrees
// via fire-and-forget global atomics.
__global__ void __launch_bounds__(P1_BS)
bucket_kernel(const int* __restrict__ edge_src,
              const int* __restrict__ edge_dst,
              int* __restrict__ cursorA,
              int* __restrict__ pairs,
              int* __restrict__ deg, int n_edges) {
    __shared__ int s_cnt[NB];
    __shared__ int s_base[NB];
    __shared__ int s_buf[NB * P1_CAP];   // 782*16*4 = 50 KB

    int tile = blockIdx.x * P1_TILE;
    if (tile >= n_edges) return;

    for (int b = threadIdx.x; b < NB; b += P1_BS) s_cnt[b] = 0;
    __syncthreads();

    const int4* src4 = reinterpret_cast<const int4*>(edge_src);
    const int4* dst4 = reinterpret_cast<const int4*>(edge_dst);
    int tileq = blockIdx.x * (P1_TILE / 4);
    #pragma unroll
    for (int j = 0; j < P1_TILE / 4 / P1_BS; ++j) {
        int iq = tileq + j * P1_BS + threadIdx.x;
        if (iq * 4 < n_edges) {
            int4 sv = src4[iq];
            int4 dv = dst4[iq];
            int ss[4] = {sv.x, sv.y, sv.z, sv.w};
            int dd[4] = {dv.x, dv.y, dv.z, dv.w};
            #pragma unroll
            for (int u = 0; u < 4; ++u) {
                int b = dd[u] >> BSH;
                int packed = (ss[u] << BSH) | (dd[u] & BMASK);
                atomicAdd(&deg[dd[u]], 1);            // no-rtn global atomic
                int p = atomicAdd(&s_cnt[b], 1);
                if (p < P1_CAP) {
                    s_buf[b * P1_CAP + p] = packed;
                } else {
                    int gp = atomicAdd(&cursorA[b], 1);   // rare overflow
                    pairs[gp] = packed;
                }
            }
        }
    }
    __syncthreads();

    for (int b = threadIdx.x; b < NB; b += P1_BS) {
        int c = min(s_cnt[b], P1_CAP);
        s_cnt[b] = c;
        s_base[b] = atomicAdd(&cursorA[b], c);
    }
    __syncthreads();

    // slot-parallel drain: 12512 slots / 512 threads = ~25 rounds
    for (int idx = threadIdx.x; idx < NB * P1_CAP; idx += P1_BS) {
        int b = idx >> 4;                 // P1_CAP == 16
        int slot = idx & (P1_CAP - 1);
        if (slot < s_cnt[b])
            pairs[s_base[b] + slot] = s_buf[idx];
    }
}

// Pass 2: pure streaming — dinv + bf16 sfeat rows from deg/feat.
// 4 lanes per node; wave touches 16 nodes = 2 KB contiguous feat reads.
__global__ void __launch_bounds__(256)
prep_kernel(const int* __restrict__ deg,
            const float* __restrict__ feat,
            float* __restrict__ dinv,
            unsigned* __restrict__ sfeat) {
    int gid = blockIdx.x * 256 + threadIdx.x;
    int node = gid >> 2;
    int q = gid & 3;
    if (node >= N_NODES) return;
    float dvv = rsqrtf(fmaxf((float)deg[node], 1.0f));
    if (q == 0) dinv[node] = dvv;
    const float4* feat4 = reinterpret_cast<const float4*>(feat);
    uint4* sf4 = reinterpret_cast<uint4*>(sfeat);
    float4 fa = feat4[node * 8 + 2 * q];
    float4 fb = feat4[node * 8 + 2 * q + 1];
    uint4 pk;
    pk.x = pack_bf16(fa.x * dvv, fa.y * dvv);
    pk.y = pack_bf16(fa.z * dvv, fa.w * dvv);
    pk.z = pack_bf16(fb.x * dvv, fb.y * dvv);
    pk.w = pack_bf16(fb.z * dvv, fb.w * dvv);
    sf4[node * 4 + q] = pk;
}

// Pass 3: one WG per bucket — edge-parallel gather, divergence-free.
// 4 lanes per edge (lane q handles 8 feats = one uint4 per edge),
// native LDS ds_add_f32 into padded acc (atomicAdd on the __shared__
// array directly — NOT unsafeAtomicAdd on a generic pointer, which
// emitted flat atomics and cost 339 us in R3), then fused Bernstein
// epilogue from LDS.
__global__ void __launch_bounds__(256)
gather_acc_kernel(const int* __restrict__ pairs,
                  const int* __restrict__ cursorA,
                  const float* __restrict__ feat,
                  const unsigned* __restrict__ sfeat,
                  const float* __restrict__ dinv,
                  float* __restrict__ out) {
    __shared__ float acc[128 * ACCW];   // 16.9 KB, padded rows

    int b = blockIdx.x;
    int t = threadIdx.x;
    int base = b * CAPB;
    int cnt = min(cursorA[b] - base, CAPB);

    for (int i = t; i < 128 * ACCW; i += 256) acc[i] = 0.f;
    __syncthreads();

    int q = t & 3;
    int eg = t >> 2;                    // 0..63: edge slot within stride-64 grid
    const uint4* sf4 = reinterpret_cast<const uint4*>(sfeat);

    #define ADD8(a0, r)                                                   \
        atomicAdd(&acc[(a0) + 0], __uint_as_float((r).x << 16));          \
        atomicAdd(&acc[(a0) + 1], __uint_as_float((r).x & 0xFFFF0000u));  \
        atomicAdd(&acc[(a0) + 2], __uint_as_float((r).y << 16));          \
        atomicAdd(&acc[(a0) + 3], __uint_as_float((r).y & 0xFFFF0000u));  \
        atomicAdd(&acc[(a0) + 4], __uint_as_float((r).z << 16));          \
        atomicAdd(&acc[(a0) + 5], __uint_as_float((r).z & 0xFFFF0000u));  \
        atomicAdd(&acc[(a0) + 6], __uint_as_float((r).w << 16));          \
        atomicAdd(&acc[(a0) + 7], __uint_as_float((r).w & 0xFFFF0000u));

    int e = eg;
    for (; e + 64 < cnt; e += 128) {    // unroll-2: two independent chains
        int p0 = pairs[base + e];
        int p1 = pairs[base + e + 64];
        uint4 r0 = sf4[(p0 >> BSH) * 4 + q];
        uint4 r1 = sf4[(p1 >> BSH) * 4 + q];
        int a0 = (p0 & BMASK) * ACCW + q * 8;
        int a1 = (p1 & BMASK) * ACCW + q * 8;
        ADD8(a0, r0)
        ADD8(a1, r1)
    }
    for (; e < cnt; e += 64) {
        int p0 = pairs[base + e];
        uint4 r0 = sf4[(p0 >> BSH) * 4 + q];
        int a0 = (p0 & BMASK) * ACCW + q * 8;
        ADD8(a0, r0)
    }
    #undef ADD8
    __syncthreads();

    // fused Bernstein epilogue: out = 2*y*(x - y), y = 0.5*(x - agg*dinv)
    const v4f* featv = reinterpret_cast<const v4f*>(feat);
    v4f* outv = reinterpret_cast<v4f*>(out);
    for (int idx = t; idx < 128 * 4; idx += 256) {
        int nl = idx >> 2;
        int qq = idx & 3;
        int node = (b << BSH) + nl;
        if (node >= N_NODES) continue;
        float dvn = dinv[node];
        const float* a = &acc[nl * ACCW + qq * 8];
        v4f fa = __builtin_nontemporal_load(&featv[node * 8 + 2 * qq]);
        v4f fb = __builtin_nontemporal_load(&featv[node * 8 + 2 * qq + 1]);
        v4f oa, ob;
        float y;
        y = 0.5f * (fa.x - a[0] * dvn); oa.x = 2.0f * y * (fa.x - y);
        y = 0.5f * (fa.y - a[1] * dvn); oa.y = 2.0f * y * (fa.y - y);
        y = 0.5f * (fa.z - a[2] * dvn); oa.z = 2.0f * y * (fa.z - y);
        y = 0.5f * (fa.w - a[3] * dvn); oa.w = 2.0f * y * (fa.w - y);
        y = 0.5f * (fb.x - a[4] * dvn); ob.x = 2.0f * y * (fb.x - y);
        y = 0.5f * (fb.y - a[5] * dvn); ob.y = 2.0f * y * (fb.y - y);
        y = 0.5f * (fb.z - a[6] * dvn); ob.z = 2.0f * y * (fb.z - y);
        y = 0.5f * (fb.w - a[7] * dvn); ob.w = 2.0f * y * (fb.w - y);
        __builtin_nontemporal_store(oa, &outv[node * 8 + 2 * qq]);
        __builtin_nontemporal_store(ob, &outv[node * 8 + 2 * qq + 1]);
    }
}

extern "C" void kernel_launch(void* const* d_in, const int* in_sizes, int n_in,
                              void* d_out, int out_size, void* d_ws, size_t ws_size,
                              hipStream_t stream) {
    const float* feat = (const float*)d_in[0];
    const int* edge_src = (const int*)d_in[1];
    const int* edge_dst = (const int*)d_in[2];
    float* out = (float*)d_out;

    int* ws = (int*)d_ws;
    int* cursorA    = ws;                              // 1024
    int* deg        = cursorA + 1024;                  // N_NODES
    float* dinv     = (float*)(deg + N_NODES);         // N_NODES
    int* pairs      = (int*)(dinv + N_NODES);          // NB*CAPB
    unsigned* sfeat = (unsigned*)(pairs + NB * CAPB);  // N_NODES*16

    {
        int blocks = (N_NODES + 255) / 256;   // 391 (covers NB too)
        init_kernel<<<blocks, 256, 0, stream>>>(cursorA, deg);
    }
    {
        int blocks = (N_EDGES + P1_TILE - 1) / P1_TILE;   // 391
        bucket_kernel<<<blocks, P1_BS, 0, stream>>>(edge_src, edge_dst,
                                                    cursorA, pairs, deg, N_EDGES);
    }
    {
        int total = N_NODES * 4;
        int blocks = (total + 255) / 256;     // 1563
        prep_kernel<<<blocks, 256, 0, stream>>>(deg, feat, dinv, sfeat);
    }
    gather_acc_kernel<<<NB, 256, 0, stream>>>(pairs, cursorA, feat, sfeat,
                                              dinv, out);
}

// Round 6
// 112.960 us; speedup vs baseline: 4.2999x; 4.2999x over previous
//
#include <hip/hip_runtime.h>

#define N_NODES 100000
#define N_EDGES 1600000
#define D_FEAT 32

#define BSH 7                 // bucket = dst >> 7  (128 nodes per bucket)
#define BMASK 127
#define NB 782                // ceil(100000/128)
#define CAPB 2432             // per-bucket capacity (mean 2048, ~8.5 sigma pad)

#define P1_BS 1024            // 4 edges/thread (1 int4 pair per thread)
#define P1_TILE 4096
#define P1_CAP 16             // staging per bucket per block (mean ~5.2)

// ws layout (4-byte words):
//   cursorA [1024]        int    per-bucket fill cursors (init to b*CAPB)
//   pairs   [NB*CAPB]     int    packed (src<<7)|(dst&127), bucket-grouped
//   sfeat   [N_NODES*16]  uint   bf16-packed feat*dinv (2 feats per uint)
//
// NOTE (R3/R5 lesson): LDS float atomicAdd — both unsafeAtomicAdd on a
// generic pointer AND plain atomicAdd on the __shared__ array — compiles
// to a non-DS path here (VALUBusy 1%, SQ_LDS_BANK_CONFLICT exactly 0,
// 340 us). Edge-parallel LDS-atomic accumulation is not viable; scattered
// global atomics (deg counting) cost ~55 us from cross-XCD line ping-pong.
// Hence: sorted per-node gather, degrees from per-bucket LDS histograms.

typedef float v4f __attribute__((ext_vector_type(4)));   // native vec for nontemporal builtins

static __device__ __forceinline__ unsigned pack_bf16(float a, float b) {
    unsigned ua = __float_as_uint(a);
    unsigned ub = __float_as_uint(b);
    ua = (ua + 0x7FFFu + ((ua >> 16) & 1u)) >> 16;   // RNE
    ub = (ub + 0x7FFFu + ((ub >> 16) & 1u)) >> 16;
    return (ua & 0xFFFFu) | (ub << 16);
}

__global__ void init_kernel(int* __restrict__ cursorA) {
    int b = blockIdx.x * blockDim.x + threadIdx.x;
    if (b < NB) cursorA[b] = b * CAPB;
}

// Pass 1: bucket edges by dst>>7 with LDS staging -> coalesced runs into
// fixed per-bucket regions. 1024 threads, 4 edges/thread: halves the
// per-block sequential depth vs the 512-thread version. Slot-parallel drain.
__global__ void __launch_bounds__(P1_BS)
bucket_kernel(const int* __restrict__ edge_src,
              const int* __restrict__ edge_dst,
              int* __restrict__ cursorA,
              int* __restrict__ pairs, int n_edges) {
    __shared__ int s_cnt[NB];
    __shared__ int s_base[NB];
    __shared__ int s_buf[NB * P1_CAP];   // 782*16*4 = 50 KB

    int tile = blockIdx.x * P1_TILE;
    if (tile >= n_edges) return;

    for (int b = threadIdx.x; b < NB; b += P1_BS) s_cnt[b] = 0;
    __syncthreads();

    const int4* src4 = reinterpret_cast<const int4*>(edge_src);
    const int4* dst4 = reinterpret_cast<const int4*>(edge_dst);
    int tileq = blockIdx.x * (P1_TILE / 4);
    {
        int iq = tileq + threadIdx.x;            // 1024 int4s == 4096 edges
        if (iq * 4 < n_edges) {
            int4 sv = src4[iq];
            int4 dv = dst4[iq];
            int ss[4] = {sv.x, sv.y, sv.z, sv.w};
            int dd[4] = {dv.x, dv.y, dv.z, dv.w};
            #pragma unroll
            for (int u = 0; u < 4; ++u) {
                int b = dd[u] >> BSH;
                int packed = (ss[u] << BSH) | (dd[u] & BMASK);
                int p = atomicAdd(&s_cnt[b], 1);
                if (p < P1_CAP) {
                    s_buf[b * P1_CAP + p] = packed;
                } else {
                    int gp = atomicAdd(&cursorA[b], 1);   // rare overflow
                    pairs[gp] = packed;
                }
            }
        }
    }
    __syncthreads();

    for (int b = threadIdx.x; b < NB; b += P1_BS) {
        int c = min(s_cnt[b], P1_CAP);
        s_cnt[b] = c;
        s_base[b] = atomicAdd(&cursorA[b], c);
    }
    __syncthreads();

    // slot-parallel drain: 12512 slots / 1024 threads = 13 rounds
    for (int idx = threadIdx.x; idx < NB * P1_CAP; idx += P1_BS) {
        int b = idx >> 4;                 // P1_CAP == 16
        int slot = idx & (P1_CAP - 1);
        if (slot < s_cnt[b])
            pairs[s_base[b] + slot] = s_buf[idx];
    }
}

// Pass 2: one WG per bucket — degree histogram + bf16 sfeat rows.
__global__ void __launch_bounds__(512)
prep_kernel(const int* __restrict__ pairs,
            const int* __restrict__ cursorA,
            const float* __restrict__ feat,
            unsigned* __restrict__ sfeat) {
    __shared__ int h[128];
    __shared__ float dv_s[128];

    int b = blockIdx.x;
    int t = threadIdx.x;
    int base = b * CAPB;
    int cnt = min(cursorA[b] - base, CAPB);

    if (t < 128) h[t] = 0;
    __syncthreads();
    for (int i = t; i < cnt; i += 512)
        atomicAdd(&h[pairs[base + i] & BMASK], 1);
    __syncthreads();

    if (t < 128)
        dv_s[t] = rsqrtf(fmaxf((float)h[t], 1.0f));
    __syncthreads();

    // bf16 sfeat rows: sfeat[n] = bf16(feat[n] * dinv[n]), uint4 per 8 feats
    const float4* feat4 = reinterpret_cast<const float4*>(feat);
    uint4* sf4 = reinterpret_cast<uint4*>(sfeat);
    for (int idx = t; idx < 128 * 4; idx += 512) {
        int nl = idx >> 2;
        int q = idx & 3;
        int node = (b << BSH) + nl;
        if (node >= N_NODES) continue;
        float dvv = dv_s[nl];
        float4 fa = feat4[node * 8 + 2 * q];
        float4 fb = feat4[node * 8 + 2 * q + 1];
        uint4 pk;
        pk.x = pack_bf16(fa.x * dvv, fa.y * dvv);
        pk.y = pack_bf16(fa.z * dvv, fa.w * dvv);
        pk.z = pack_bf16(fb.x * dvv, fb.y * dvv);
        pk.w = pack_bf16(fb.z * dvv, fb.w * dvv);
        sf4[node * 4 + q] = pk;
    }
}

// Pass 3: one WG (512 threads) per bucket — fused counting sort (LDS only)
// + gather + Bernstein epilogue. 512 threads: sort rounds halve, and the
// gather is exactly one (node, quad) item per thread -> block wall time
// ~= max node degree, no stacked passes.
__global__ void __launch_bounds__(512)
sortgather_kernel(const int* __restrict__ pairs,
                  const int* __restrict__ cursorA,
                  const float* __restrict__ feat,
                  const unsigned* __restrict__ sfeat,
                  float* __restrict__ out) {
    __shared__ int buf[CAPB];     // 9.5 KB
    __shared__ int outb[CAPB];    // 9.5 KB  (dst-sorted srcs)
    __shared__ int h[128];
    __shared__ int sc[128];
    __shared__ int cur[128];
    __shared__ float dv_s[128];

    int b = blockIdx.x;
    int t = threadIdx.x;
    int base = b * CAPB;
    int cnt = min(cursorA[b] - base, CAPB);

    if (t < 128) h[t] = 0;
    __syncthreads();
    for (int i = t; i < cnt; i += 512) {
        int p = pairs[base + i];
        buf[i] = p;
        atomicAdd(&h[p & BMASK], 1);
    }
    __syncthreads();

    // inclusive scan of h into sc: single wave, 2 bins/lane, shfl_up scan
    if (t < 64) {
        int a  = h[2 * t];
        int b2 = h[2 * t + 1];
        int s = a + b2;
        #pragma unroll
        for (int off = 1; off < 64; off <<= 1) {
            int x = __shfl_up(s, off);
            if (t >= off) s += x;
        }
        sc[2 * t]     = s - b2;   // inclusive through bin 2t
        sc[2 * t + 1] = s;        // inclusive through bin 2t+1
    }
    __syncthreads();
    if (t < 128) {
        cur[t] = sc[t] - h[t];                 // exclusive
        dv_s[t] = rsqrtf(fmaxf((float)h[t], 1.0f));
    }
    __syncthreads();

    for (int i = t; i < cnt; i += 512) {
        int p = buf[i];
        int pos = atomicAdd(&cur[p & BMASK], 1);
        outb[pos] = p >> BSH;
    }
    __syncthreads();

    // gather: one (node, quad) per thread; srcs from LDS outb
    const uint4* sf4 = reinterpret_cast<const uint4*>(sfeat);
    const v4f* featv = reinterpret_cast<const v4f*>(feat);
    v4f* outv = reinterpret_cast<v4f*>(out);

    {
        int nl = t >> 2;                        // 0..127
        int q = t & 3;
        int node = (b << BSH) + nl;
        if (node < N_NODES) {
            int en = sc[nl];
            int k = en - h[nl];
            float a0 = 0.f, a1 = 0.f, a2 = 0.f, a3 = 0.f;
            float a4 = 0.f, a5 = 0.f, a6 = 0.f, a7 = 0.f;

            #define ACC(r)                                                 \
                a0 += __uint_as_float((r).x << 16);                        \
                a1 += __uint_as_float((r).x & 0xFFFF0000u);                \
                a2 += __uint_as_float((r).y << 16);                        \
                a3 += __uint_as_float((r).y & 0xFFFF0000u);                \
                a4 += __uint_as_float((r).z << 16);                        \
                a5 += __uint_as_float((r).z & 0xFFFF0000u);                \
                a6 += __uint_as_float((r).w << 16);                        \
                a7 += __uint_as_float((r).w & 0xFFFF0000u);

            for (; k + 7 < en; k += 8) {
                int s0 = outb[k],     s1 = outb[k + 1];
                int s2 = outb[k + 2], s3 = outb[k + 3];
                int s4 = outb[k + 4], s5 = outb[k + 5];
                int s6 = outb[k + 6], s7 = outb[k + 7];
                uint4 r0 = sf4[s0 * 4 + q];
                uint4 r1 = sf4[s1 * 4 + q];
                uint4 r2 = sf4[s2 * 4 + q];
                uint4 r3 = sf4[s3 * 4 + q];
                uint4 r4 = sf4[s4 * 4 + q];
                uint4 r5 = sf4[s5 * 4 + q];
                uint4 r6 = sf4[s6 * 4 + q];
                uint4 r7 = sf4[s7 * 4 + q];
                ACC(r0) ACC(r1) ACC(r2) ACC(r3)
                ACC(r4) ACC(r5) ACC(r6) ACC(r7)
            }
            for (; k + 3 < en; k += 4) {
                int s0 = outb[k],     s1 = outb[k + 1];
                int s2 = outb[k + 2], s3 = outb[k + 3];
                uint4 r0 = sf4[s0 * 4 + q];
                uint4 r1 = sf4[s1 * 4 + q];
                uint4 r2 = sf4[s2 * 4 + q];
                uint4 r3 = sf4[s3 * 4 + q];
                ACC(r0) ACC(r1) ACC(r2) ACC(r3)
            }
            for (; k < en; ++k) {
                uint4 r = sf4[outb[k] * 4 + q];
                ACC(r)
            }
            #undef ACC

            float dvn = dv_s[nl];
            v4f fa = __builtin_nontemporal_load(&featv[node * 8 + 2 * q]);
            v4f fb = __builtin_nontemporal_load(&featv[node * 8 + 2 * q + 1]);
            v4f oa, ob;
            float y;
            y = 0.5f * (fa.x - a0 * dvn); oa.x = 2.0f * y * (fa.x - y);
            y = 0.5f * (fa.y - a1 * dvn); oa.y = 2.0f * y * (fa.y - y);
            y = 0.5f * (fa.z - a2 * dvn); oa.z = 2.0f * y * (fa.z - y);
            y = 0.5f * (fa.w - a3 * dvn); oa.w = 2.0f * y * (fa.w - y);
            y = 0.5f * (fb.x - a4 * dvn); ob.x = 2.0f * y * (fb.x - y);
            y = 0.5f * (fb.y - a5 * dvn); ob.y = 2.0f * y * (fb.y - y);
            y = 0.5f * (fb.z - a6 * dvn); ob.z = 2.0f * y * (fb.z - y);
            y = 0.5f * (fb.w - a7 * dvn); ob.w = 2.0f * y * (fb.w - y);
            __builtin_nontemporal_store(oa, &outv[node * 8 + 2 * q]);
            __builtin_nontemporal_store(ob, &outv[node * 8 + 2 * q + 1]);
        }
    }
}

extern "C" void kernel_launch(void* const* d_in, const int* in_sizes, int n_in,
                              void* d_out, int out_size, void* d_ws, size_t ws_size,
                              hipStream_t stream) {
    const float* feat = (const float*)d_in[0];
    const int* edge_src = (const int*)d_in[1];
    const int* edge_dst = (const int*)d_in[2];
    float* out = (float*)d_out;

    int* ws = (int*)d_ws;
    int* cursorA    = ws;                              // 1024
    int* pairs      = cursorA + 1024;                  // NB*CAPB
    unsigned* sfeat = (unsigned*)(pairs + NB * CAPB);  // N_NODES*16

    init_kernel<<<1, 1024, 0, stream>>>(cursorA);
    {
        int blocks = (N_EDGES + P1_TILE - 1) / P1_TILE;   // 391
        bucket_kernel<<<blocks, P1_BS, 0, stream>>>(edge_src, edge_dst,
                                                    cursorA, pairs, N_EDGES);
    }
    prep_kernel<<<NB, 512, 0, stream>>>(pairs, cursorA, feat, sfeat);
    sortgather_kernel<<<NB, 512, 0, stream>>>(pairs, cursorA, feat, sfeat, out);
}